// Round 1
// baseline (403.963 us; speedup 1.0000x reference)
//
#include <hip/hip_runtime.h>
#include <stdint.h>
#include <limits.h>

#define BATCH 64
#define HH 512
#define NR 256
#define RPW 4                  // contiguous rows per wave (run-length axis)
#define BAND (RPW * 2)         // 8 rows per block: 2 rowsets x 2 column-halves = 4 waves
#define NBANDS (HH / BAND)     // 64

// LDS aperture: low 32 bits of a generic pointer to __shared__ = LDS offset.
__device__ __forceinline__ uint32_t lds_off(const void* p) {
    return (uint32_t)(uintptr_t)p;
}

// Native fire-and-forget LDS fp32 atomics into 4 comp-major tables of 257
// floats (strides 1028 B). NO "memory" clobber: ordering vs the merge phase
// is enforced by the explicit waitcnt asm + __syncthreads.
__device__ __forceinline__ void lds_add4(uint32_t addr, float v0, float v1,
                                         float v2, float v3) {
    asm volatile(
        "ds_add_f32 %0, %1\n\t"
        "ds_add_f32 %0, %2 offset:1028\n\t"
        "ds_add_f32 %0, %3 offset:2056\n\t"
        "ds_add_f32 %0, %4 offset:3084"
        :: "v"(addr), "v"(v0), "v"(v1), "v"(v2), "v"(v3));
}

__device__ __forceinline__ void gl_add(float* p, float v) {
    asm volatile("global_atomic_add_f32 %0, %1, off"
                 :: "v"(p), "v"(v) : "memory");
}

// Row-streaming layout, built for MLP:
//  - lane L owns 4 consecutive columns c0 = 256*half + 4L .. +3  (16-B aligned)
//  - wave owns RPW contiguous rows; all RPW*4 float4 loads are issued in one
//    straight-line block (no break, no loads under divergent branches) so the
//    compiler keeps up to 16 KB in flight per wave.
//  - per-column run-length accumulation along dy (bin changes <=1/row), flushed
//    to the 4x257 LDS table via ds_add_f32; bin 256 = overflow bucket (dropped).
//  - corner lane-strips that are entirely bin>=256 skip loads+compute entirely
//    (one per-lane predicate hoisted out of the row loop).
__global__ __launch_bounds__(256, 4) void frc_rows(
    const float* __restrict__ f1r, const float* __restrict__ f1i,
    const float* __restrict__ f2r, const float* __restrict__ f2i,
    float* __restrict__ gacc /* [BATCH][4][NR] */)
{
    __shared__ float s_acc[4 * 257];   // [comp][bin], bin 256 = overflow
    for (int i = threadIdx.x; i < 4 * 257; i += 256) s_acc[i] = 0.f;
    __syncthreads();

    const int b    = blockIdx.y;
    const int band = blockIdx.x;
    const int w    = threadIdx.x >> 6;
    const int lane = threadIdx.x & 63;
    const int half   = w & 1;          // 0: cols 0..255, 1: cols 256..511
    const int rowset = w >> 1;         // which 4-row strip of the band

    const int c0 = half * 256 + 4 * lane;     // first of this lane's 4 columns
    const int y0 = band * BAND + rowset * RPW;

    int d2i[4];
    #pragma unroll
    for (int j = 0; j < 4; ++j) { const int d = c0 + j - 256; d2i[j] = d * d; }
    const int mind2 = min(min(d2i[0], d2i[1]), min(d2i[2], d2i[3]));

    int mindy2 = INT_MAX;
    #pragma unroll
    for (int t = 0; t < RPW; ++t) {
        const int dy = y0 + t - 256;
        mindy2 = min(mindy2, dy * dy);
    }

    const uint32_t sbase = lds_off(s_acc);

    // Whole strip in overflow bins (bin>=256 for every row/col) -> nothing to do.
    if (mind2 + mindy2 < 65536) {
        const size_t base = (size_t)b * HH * HH + (size_t)c0;

        // ---- all loads up front: 16x global_load_dwordx4, independent ----
        float4 A1[RPW], B1[RPW], A2[RPW], B2[RPW];
        #pragma unroll
        for (int t = 0; t < RPW; ++t) {
            const size_t off = base + (size_t)(y0 + t) * HH;
            A1[t] = *(const float4*)(f1r + off);
            B1[t] = *(const float4*)(f1i + off);
            A2[t] = *(const float4*)(f2r + off);
            B2[t] = *(const float4*)(f2i + off);
        }

        // per-column run-length state (all statically indexed -> registers)
        float acc0[4], acc1[4], acc2[4], acc3[4];
        int cur[4];
        #pragma unroll
        for (int j = 0; j < 4; ++j) {
            cur[j] = -1;
            acc0[j] = 0.f; acc1[j] = 0.f; acc2[j] = 0.f; acc3[j] = 0.f;
        }

        #pragma unroll
        for (int t = 0; t < RPW; ++t) {
            const int dy  = y0 + t - 256;
            const int dy2 = dy * dy;
            const float a1[4] = {A1[t].x, A1[t].y, A1[t].z, A1[t].w};
            const float b1[4] = {B1[t].x, B1[t].y, B1[t].z, B1[t].w};
            const float a2[4] = {A2[t].x, A2[t].y, A2[t].z, A2[t].w};
            const float b2[4] = {B2[t].x, B2[t].y, B2[t].z, B2[t].w};

            #pragma unroll
            for (int j = 0; j < 4; ++j) {
                const int r2 = d2i[j] + dy2;          // <= 131072, exact in fp32
                int bin = (int)sqrtf((float)r2);
                bin -= (bin * bin > r2);
                bin += ((bin + 1) * (bin + 1) <= r2);
                if (bin > 256) bin = 256;

                const float cr = a1[j] * a2[j] + b1[j] * b2[j];
                const float ci = b1[j] * a2[j] - a1[j] * b2[j];
                const float p1 = a1[j] * a1[j] + b1[j] * b1[j];
                const float p2 = a2[j] * a2[j] + b2[j] * b2[j];

                if (bin != cur[j]) {
                    if (cur[j] >= 0)
                        lds_add4(sbase + 4u * (uint32_t)cur[j],
                                 acc0[j], acc1[j], acc2[j], acc3[j]);
                    acc0[j] = 0.f; acc1[j] = 0.f; acc2[j] = 0.f; acc3[j] = 0.f;
                    cur[j] = bin;
                }
                acc0[j] += cr; acc1[j] += ci; acc2[j] += p1; acc3[j] += p2;
            }
        }

        #pragma unroll
        for (int j = 0; j < 4; ++j)
            if (cur[j] >= 0)
                lds_add4(sbase + 4u * (uint32_t)cur[j],
                         acc0[j], acc1[j], acc2[j], acc3[j]);
    }

    // Drain the asm DS ops the compiler can't see, then merge.
    asm volatile("s_waitcnt lgkmcnt(0)" ::: "memory");
    __syncthreads();

    {
        const int r = threadIdx.x;  // 256 threads -> bins 0..255 (drop 256)
        const float v0 = s_acc[0 * 257 + r];
        const float v1 = s_acc[1 * 257 + r];
        const float v2 = s_acc[2 * 257 + r];
        const float v3 = s_acc[3 * 257 + r];
        if (v0 != 0.f || v1 != 0.f || v2 != 0.f || v3 != 0.f) {
            float* g = gacc + (size_t)b * 4 * NR + r;
            gl_add(g + 0 * NR, v0);
            gl_add(g + 1 * NR, v1);
            gl_add(g + 2 * NR, v2);
            gl_add(g + 3 * NR, v3);
        }
    }
}

__global__ __launch_bounds__(NR) void frc_finalize(
    const float* __restrict__ gacc, float* __restrict__ out)
{
    const int b = blockIdx.x;
    const int r = threadIdx.x;
    const float* g = gacc + (size_t)b * 4 * NR + r;
    const float cr = g[0 * NR], ci = g[1 * NR], p1 = g[2 * NR], p2 = g[3 * NR];
    const float num = sqrtf(cr * cr + ci * ci);
    const float den = sqrtf(p1 * p2);
    out[(size_t)b * NR + r] = (den == 0.f) ? 0.f : num / den;
}

extern "C" void kernel_launch(void* const* d_in, const int* in_sizes, int n_in,
                              void* d_out, int out_size, void* d_ws, size_t ws_size,
                              hipStream_t stream) {
    const float* f1r = (const float*)d_in[0];
    const float* f1i = (const float*)d_in[1];
    const float* f2r = (const float*)d_in[2];
    const float* f2i = (const float*)d_in[3];
    float* out  = (float*)d_out;
    float* gacc = (float*)d_ws;   // BATCH*4*NR floats = 256 KiB

    (void)in_sizes; (void)n_in; (void)out_size; (void)ws_size;

    hipMemsetAsync(gacc, 0, (size_t)BATCH * 4 * NR * sizeof(float), stream);

    dim3 grid(NBANDS, BATCH);   // 64 x 64 = 4096 blocks
    frc_rows<<<grid, 256, 0, stream>>>(f1r, f1i, f2r, f2i, gacc);
    frc_finalize<<<dim3(BATCH), dim3(NR), 0, stream>>>(gacc, out);
}

// Round 2
// 253.093 us; speedup vs baseline: 1.5961x; 1.5961x over previous
//
#include <hip/hip_runtime.h>
#include <stdint.h>

#define BATCH 64
#define HH 512
#define NR 256
#define BANDH 8
#define NBANDS (256 / BANDH)   // 32 bands over dy' in [0,256)

// LDS aperture: low 32 bits of a generic pointer to __shared__ = LDS offset.
__device__ __forceinline__ uint32_t lds_off(const void* p) {
    return (uint32_t)(uintptr_t)p;
}

// Native fire-and-forget LDS fp32 atomics into 4 comp-major tables of 257
// floats (strides 1028 B). Comp-major => flushing lanes hold mostly-distinct
// consecutive bins at 4-B stride -> perfect bank spread. NO "memory" clobber:
// the compiler may (and should) hoist the next step's global loads above
// these; ordering vs the merge phase is enforced by the explicit waitcnt asm
// (which does clobber memory) + __syncthreads.
__device__ __forceinline__ void lds_add4(uint32_t addr, float v0, float v1,
                                         float v2, float v3) {
    asm volatile(
        "ds_add_f32 %0, %1\n\t"
        "ds_add_f32 %0, %2 offset:1028\n\t"
        "ds_add_f32 %0, %3 offset:2056\n\t"
        "ds_add_f32 %0, %4 offset:3084"
        :: "v"(addr), "v"(v0), "v"(v1), "v"(v2), "v"(v3));
}

// 4-fold mirror + column-run-length scatter. IDENTICAL to the proven 110-us
// kernel except the merge: partials go to a PRIVATE per-block slice of the
// workspace with plain coalesced stores — zero global atomics. The previous
// global_atomic_add merge (2M fire-and-forget adds into 64 KB shared by
// blocks on all 8 XCDs) is the suspected hidden serializer: every pipe
// (VALU/HBM/LDS) idles <10% while the dispatch drains cross-XCD atomics.
__global__ __launch_bounds__(256) void frc_fold(
    const float* __restrict__ f1r, const float* __restrict__ f1i,
    const float* __restrict__ f2r, const float* __restrict__ f2i,
    float* __restrict__ gpart /* [NBANDS][BATCH][4][NR] */)
{
    __shared__ float s_acc[4 * 257];   // [comp][bin], bin 256 = overflow
    for (int i = threadIdx.x; i < 4 * 257; i += 256) s_acc[i] = 0.f;
    __syncthreads();

    const int b    = blockIdx.y;
    const int band = blockIdx.x;
    const int w    = threadIdx.x >> 6;
    const int lane = threadIdx.x & 63;
    const int dx   = w * 64 + lane;          // 0..255
    const int dx2  = dx * dx;
    const int wmin2 = (w * 64) * (w * 64);   // min dx^2 in this wave
    const float mx = (dx == 0) ? 0.f : 1.f;  // dx=0 is its own x-mirror

    const int dy0 = band * BANDH;
    const size_t ib = (size_t)b * HH * HH;
    const uint32_t sbase = lds_off(s_acc);

    float acr = 0.f, aci = 0.f, ap1 = 0.f, ap2 = 0.f;
    int cur = -1;

    for (int dy = dy0; dy < dy0 + BANDH; ++dy) {
        if (wmin2 + dy * dy >= 65536) break;  // whole wave in overflow bins

        const int r2 = dx2 + dy * dy;         // < 2^18, exact in fp32
        int bin = (int)sqrtf((float)r2);
        bin -= (bin * bin > r2);
        bin += ((bin + 1) * (bin + 1) <= r2);
        if (bin > 256) bin = 256;

        const float my = (dy == 0) ? 0.f : 1.f;  // dy=0 is its own y-mirror

        const size_t rp = ib + (size_t)(256 + dy) * HH;
        const size_t rm = ib + (size_t)(256 - dy) * HH;
        const int xp = 256 + dx;   // 256..511
        const int xm = 256 - dx;   // 1..256

        const float A1 = f1r[rp + xp], B1 = f1i[rp + xp];
        const float A2 = f2r[rp + xp], B2 = f2i[rp + xp];
        const float C1 = f1r[rp + xm], D1 = f1i[rp + xm];
        const float C2 = f2r[rp + xm], D2 = f2i[rp + xm];
        const float E1 = f1r[rm + xp], G1 = f1i[rm + xp];
        const float E2 = f2r[rm + xp], G2 = f2i[rm + xp];
        const float P1 = f1r[rm + xm], Q1 = f1i[rm + xm];
        const float P2 = f2r[rm + xm], Q2 = f2i[rm + xm];

        // folded products over up to 4 mirror pixels
        float scr = A1 * A2 + B1 * B2;
        float sci = B1 * A2 - A1 * B2;
        float sp1 = A1 * A1 + B1 * B1;
        float sp2 = A2 * A2 + B2 * B2;

        scr += mx * (C1 * C2 + D1 * D2);
        sci += mx * (D1 * C2 - C1 * D2);
        sp1 += mx * (C1 * C1 + D1 * D1);
        sp2 += mx * (C2 * C2 + D2 * D2);

        scr += my * (E1 * E2 + G1 * G2);
        sci += my * (G1 * E2 - E1 * G2);
        sp1 += my * (E1 * E1 + G1 * G1);
        sp2 += my * (E2 * E2 + G2 * G2);

        const float mxy = mx * my;
        scr += mxy * (P1 * P2 + Q1 * Q2);
        sci += mxy * (Q1 * P2 - P1 * Q2);
        sp1 += mxy * (P1 * P1 + Q1 * Q1);
        sp2 += mxy * (P2 * P2 + Q2 * Q2);

        if (bin != cur) {
            if (cur >= 0)
                lds_add4(sbase + 4u * (uint32_t)cur, acr, aci, ap1, ap2);
            acr = 0.f; aci = 0.f; ap1 = 0.f; ap2 = 0.f;
            cur = bin;
        }
        acr += scr; aci += sci; ap1 += sp1; ap2 += sp2;
    }
    if (cur >= 0)
        lds_add4(sbase + 4u * (uint32_t)cur, acr, aci, ap1, ap2);

    // Drain the asm DS ops the compiler can't see, then merge.
    asm volatile("s_waitcnt lgkmcnt(0)" ::: "memory");
    __syncthreads();

    {
        // Plain coalesced stores into this block's private slice. Blocks that
        // did no work still write their (zeroed) table — no memset needed.
        const int r = threadIdx.x;  // 256 threads -> bins 0..255 (drop 256)
        float* g = gpart + ((size_t)(band * BATCH + b) * 4) * NR + r;
        g[0 * NR] = s_acc[0 * 257 + r];
        g[1 * NR] = s_acc[1 * 257 + r];
        g[2 * NR] = s_acc[2 * 257 + r];
        g[3 * NR] = s_acc[3 * 257 + r];
    }
}

__global__ __launch_bounds__(NR) void frc_finalize(
    const float* __restrict__ gpart, float* __restrict__ out)
{
    const int b = blockIdx.x;
    const int r = threadIdx.x;
    float cr = 0.f, ci = 0.f, p1 = 0.f, p2 = 0.f;
    for (int band = 0; band < NBANDS; ++band) {
        const float* g = gpart + ((size_t)(band * BATCH + b) * 4) * NR + r;
        cr += g[0 * NR];
        ci += g[1 * NR];
        p1 += g[2 * NR];
        p2 += g[3 * NR];
    }
    const float num = sqrtf(cr * cr + ci * ci);
    const float den = sqrtf(p1 * p2);
    out[(size_t)b * NR + r] = (den == 0.f) ? 0.f : num / den;
}

extern "C" void kernel_launch(void* const* d_in, const int* in_sizes, int n_in,
                              void* d_out, int out_size, void* d_ws, size_t ws_size,
                              hipStream_t stream) {
    const float* f1r = (const float*)d_in[0];
    const float* f1i = (const float*)d_in[1];
    const float* f2r = (const float*)d_in[2];
    const float* f2i = (const float*)d_in[3];
    float* out   = (float*)d_out;
    float* gpart = (float*)d_ws;   // NBANDS*BATCH*4*NR floats = 8 MiB

    (void)in_sizes; (void)n_in; (void)out_size; (void)ws_size;

    dim3 grid(NBANDS, BATCH);   // 32 x 64 = 2048 blocks, 8/CU
    frc_fold<<<grid, 256, 0, stream>>>(f1r, f1i, f2r, f2i, gpart);
    frc_finalize<<<dim3(BATCH), dim3(NR), 0, stream>>>(gpart, out);
}